// Round 2
// 338.402 us; speedup vs baseline: 1.0028x; 1.0028x over previous
//
#include <hip/hip_runtime.h>

// ---------------------------------------------------------------------------
// Attention: out = softmax(BETA * (X_q Wq + bq)(X_k Wk + bk)^T) (X_v Wv + bv)
// B=4, S=2048, D=1024, KEY_DIM=VALUE_DIM=1024, BETA=1/32.
// R8 = R7 with the add2 grid bug fixed (was covering half the output).
// R7: all three GEMMs on the 256x256 / BK=64 / 8-wave 8-phase template
//  (T3+T4 counted-vmcnt pipeline + T5 setprio; T2 swizzle kept from R6).
//  - per K-tile: 4 phases {ds_read subtile || stage 1 half-tile -> raw
//    s_barrier -> lgkmcnt(0) -> setprio(1) 16xMFMA setprio(0) -> barrier}.
//  - vmcnt(4) once per K-tile (2 half-tiles in flight), vmcnt(0) only at tail.
//  - PV uses split-K=2 (grid z = batch*2+khalf -> 256 blocks) + add2 reduce;
//    partials reuse the dead scores buffer.
// ---------------------------------------------------------------------------

typedef __bf16 bf16x8 __attribute__((ext_vector_type(8)));
typedef float f32x4 __attribute__((ext_vector_type(4)));

#define MIB ((size_t)1 << 20)

__device__ __forceinline__ unsigned short f2b(float f) {
  unsigned int u = __float_as_uint(f);
  return (unsigned short)((u + 0x7FFFu + ((u >> 16) & 1u)) >> 16);
}

__device__ __forceinline__ void async16(const void* g, void* l) {
  __builtin_amdgcn_global_load_lds(
      (const __attribute__((address_space(1))) unsigned int*)g,
      (__attribute__((address_space(3))) unsigned int*)l, 16, 0, 0);
}

// Raw workgroup barrier WITHOUT the compiler's vmcnt(0)/lgkmcnt(0) drain.
// Empty-asm memory fences stop the compiler from moving LDS/global ops across.
__device__ __forceinline__ void barrier_raw() {
  asm volatile("" ::: "memory");
  __builtin_amdgcn_s_barrier();
  asm volatile("" ::: "memory");
}

// Stage one 128x64 bf16 half-tile (16 KB) global->LDS; 512 threads x 2 chunks.
// LDS slot (r,c) receives global chunk c^(r&7): linear LDS dest (HW req) +
// inverse-swizzled source == swizzled layout (both-sides rule).
__device__ __forceinline__ void stage_half(
    const unsigned short* __restrict__ src, unsigned short* dst, int ld,
    int tid) {
#pragma unroll
  for (int i = 0; i < 2; ++i) {
    const int e = i * 512 + tid;
    const int r = e >> 3;
    const int cg = (e & 7) ^ (r & 7);
    async16(src + (size_t)r * ld + cg * 8, dst + e * 8);
  }
}

// One C-quadrant: 4 m-frags x 2 n-frags x 2 k-steps = 16 MFMA.
template <int MO, int NO>
__device__ __forceinline__ void quad16(f32x4 (&acc)[8][4],
                                       const bf16x8 (&AV)[4][2],
                                       const bf16x8 (&BV)[2][2]) {
#pragma unroll
  for (int mi = 0; mi < 4; ++mi)
#pragma unroll
    for (int ni = 0; ni < 2; ++ni)
#pragma unroll
      for (int ks = 0; ks < 2; ++ks)
        acc[MO + mi][NO + ni] = __builtin_amdgcn_mfma_f32_16x16x32_bf16(
            AV[mi][ks], BV[ni][ks], acc[MO + mi][NO + ni], 0, 0, 0);
}

// ---------------------------------------------------------------------------
// 256x256 tile, BK=64, 8 waves (2M x 4N), per-wave 128x64 output.
// LDS 128 KiB: [buf(2)][A0 A1 B0 B1] half-tiles of 128x64 bf16 (8192 ushorts).
// A: [M,K] bf16 row-major, Bt: [N,K] bf16 row-major, ld = row stride (elems).
// Phase schedule per K-tile t (buf = t&1):
//   P1: read av(m0-3)+bv0(n0-1) [12xb128]; stage B1(t+1); bar; lgkm0; Q(0,0)
//   P2: read bv1(n2-3) [4];             stage A1(t+1); bar; lgkm0; Q(0,2)
//   P3: read av(m4-7) [8];              stage B0(t+2); bar; lgkm0; Q(4,2)
//   P4:                                 stage A0(t+2); bar;        Q(4,0)
//       vmcnt(4) (tail: vmcnt(0)); bar
// Every slot is restaged >=1 closing barrier after its last read retired;
// vmcnt(4) at P4 leaves exactly the P3/P4 stages in flight and guarantees
// kt t+1 fully in LDS before the next P1 reads it.
// ---------------------------------------------------------------------------
__device__ __forceinline__ void gemm256_core(
    const unsigned short* __restrict__ A, const unsigned short* __restrict__ Bt,
    int K, int ld, int m0, int n0, unsigned short* lds, f32x4 (&acc)[8][4]) {
  const int tid = threadIdx.x;
  const int lane = tid & 63;
  const int wave = tid >> 6;
  const int wmh = wave >> 2;        // which A half this wave reads (0/1)
  const int wnh = (wave & 3) >> 1;  // which B half this wave reads (0/1)
  const int wno = (wave & 1) * 64;  // n offset inside the B half
  const int fr = lane & 15;
  const int q = lane >> 4;
  const int NT = K >> 6;

  auto ah = [&](int buf, int h) { return lds + buf * 32768 + h * 8192; };
  auto bh = [&](int buf, int h) { return lds + buf * 32768 + 16384 + h * 8192; };

  const unsigned short* gA[2] = {A + (size_t)m0 * ld,
                                 A + (size_t)(m0 + 128) * ld};
  const unsigned short* gB[2] = {Bt + (size_t)n0 * ld,
                                 Bt + (size_t)(n0 + 128) * ld};

  auto rdA = [&](bf16x8(&AV)[4][2], const unsigned short* aa, int ro) {
#pragma unroll
    for (int mi = 0; mi < 4; ++mi) {
      const int r = ro + mi * 16 + fr;
#pragma unroll
      for (int ks = 0; ks < 2; ++ks) {
        const int kc = (ks << 2) + q;
        AV[mi][ks] = *(const bf16x8*)&aa[r * 64 + ((kc ^ (r & 7)) << 3)];
      }
    }
  };
  auto rdB = [&](bf16x8(&BV)[2][2], const unsigned short* bb, int ro) {
#pragma unroll
    for (int ni = 0; ni < 2; ++ni) {
      const int r = ro + ni * 16 + fr;
#pragma unroll
      for (int ks = 0; ks < 2; ++ks) {
        const int kc = (ks << 2) + q;
        BV[ni][ks] = *(const bf16x8*)&bb[r * 64 + ((kc ^ (r & 7)) << 3)];
      }
    }
  };

  // Prologue: kt0 {B0,A0,B1,A1}, kt1 {B0,A0}; allow kt1's 2 stages in flight.
  stage_half(gB[0], bh(0, 0), ld, tid);
  stage_half(gA[0], ah(0, 0), ld, tid);
  stage_half(gB[1], bh(0, 1), ld, tid);
  stage_half(gA[1], ah(0, 1), ld, tid);
  stage_half(gB[0] + 64, bh(1, 0), ld, tid);
  stage_half(gA[0] + 64, ah(1, 0), ld, tid);
  asm volatile("s_waitcnt vmcnt(4)" ::: "memory");
  barrier_raw();

  for (int t = 0; t < NT; ++t) {
    const int buf = t & 1;
    const unsigned short* a = ah(buf, wmh);
    const unsigned short* b = bh(buf, wnh);
    bf16x8 av[4][2], bv0[2][2], bv1[2][2];

    // ---- P1
    rdA(av, a, 0);
    rdB(bv0, b, wno);
    if (t + 1 < NT)
      stage_half(gB[1] + (size_t)(t + 1) * 64, bh((t + 1) & 1, 1), ld, tid);
    asm volatile("s_waitcnt lgkmcnt(8)" ::: "memory");
    barrier_raw();
    asm volatile("s_waitcnt lgkmcnt(0)" ::: "memory");
    __builtin_amdgcn_s_setprio(1);
    quad16<0, 0>(acc, av, bv0);
    __builtin_amdgcn_s_setprio(0);
    barrier_raw();

    // ---- P2
    rdB(bv1, b, wno + 32);
    if (t + 1 < NT)
      stage_half(gA[1] + (size_t)(t + 1) * 64, ah((t + 1) & 1, 1), ld, tid);
    barrier_raw();
    asm volatile("s_waitcnt lgkmcnt(0)" ::: "memory");
    __builtin_amdgcn_s_setprio(1);
    quad16<0, 2>(acc, av, bv1);
    __builtin_amdgcn_s_setprio(0);
    barrier_raw();

    // ---- P3
    rdA(av, a, 64);
    if (t + 2 < NT)
      stage_half(gB[0] + (size_t)(t + 2) * 64, bh(buf, 0), ld, tid);
    barrier_raw();
    asm volatile("s_waitcnt lgkmcnt(0)" ::: "memory");
    __builtin_amdgcn_s_setprio(1);
    quad16<4, 2>(acc, av, bv1);
    __builtin_amdgcn_s_setprio(0);
    barrier_raw();

    // ---- P4
    if (t + 2 < NT)
      stage_half(gA[0] + (size_t)(t + 2) * 64, ah(buf, 0), ld, tid);
    barrier_raw();
    __builtin_amdgcn_s_setprio(1);
    quad16<4, 0>(acc, av, bv0);
    __builtin_amdgcn_s_setprio(0);
    if (t + 2 < NT) {
      asm volatile("s_waitcnt vmcnt(4)" ::: "memory");
    } else if (t + 1 < NT) {
      asm volatile("s_waitcnt vmcnt(0)" ::: "memory");
    }
    barrier_raw();
  }
}

// fp32 epilogue: C/D layout col = lane&15 (+16*ni), row = (lane>>4)*4+r (+16*mi)
__device__ __forceinline__ void store_f32(float* __restrict__ C, int ldc,
                                          int m0, int n0,
                                          const f32x4 (&acc)[8][4]) {
  const int tid = threadIdx.x;
  const int lane = tid & 63;
  const int wave = tid >> 6;
  const int wm = (wave >> 2) * 128;
  const int wn = (wave & 3) * 64;
  const int fr = lane & 15;
  const int q4 = (lane >> 4) * 4;
#pragma unroll
  for (int mi = 0; mi < 8; ++mi) {
    const int rowb = m0 + wm + mi * 16 + q4;
#pragma unroll
    for (int ni = 0; ni < 4; ++ni) {
      const int col = n0 + wn + ni * 16 + fr;
#pragma unroll
      for (int r = 0; r < 4; ++r)
        C[(size_t)(rowb + r) * ldc + col] = acc[mi][ni][r];
    }
  }
}

// ---------------------------------------------------------------------------
// Merged projection GEMM, 256x256 tiles, grid (4, 32, 3): z selects {q,k,v}.
// z=0,1: bf16 row-major out [8192,1024]; z=2: vT[b][n][s] transposed out.
// ---------------------------------------------------------------------------
struct ProjArgs {
  const unsigned short* A[3];
  const unsigned short* Bt[3];
  unsigned short* C[3];
  const float* bias[3];
};

__global__ __launch_bounds__(512, 2) void proj_gemm8(ProjArgs p) {
  __shared__ __align__(16) unsigned short lds[65536];
  const int z = blockIdx.z;
  const int m0 = blockIdx.y * 256;
  const int n0 = blockIdx.x * 256;

  f32x4 acc[8][4] = {};
  gemm256_core(p.A[z], p.Bt[z], 1024, 1024, m0, n0, lds, acc);

  const int tid = threadIdx.x;
  const int lane = tid & 63;
  const int wave = tid >> 6;
  const int wm = (wave >> 2) * 128;
  const int wn = (wave & 3) * 64;
  const int fr = lane & 15;
  const int q4 = (lane >> 4) * 4;
  const float* bias = p.bias[z];

  if (z != 2) {
    unsigned short* C = p.C[z];
#pragma unroll
    for (int ni = 0; ni < 4; ++ni) {
      const int col = n0 + wn + ni * 16 + fr;
      const float bb = bias[col];
#pragma unroll
      for (int mi = 0; mi < 8; ++mi) {
        const int rowb = m0 + wm + mi * 16 + q4;
#pragma unroll
        for (int r = 0; r < 4; ++r)
          C[(size_t)(rowb + r) * 1024 + col] = f2b(acc[mi][ni][r] + bb);
      }
    }
  } else {
    // vT: per-batch [1024, 2048]; 256-row tile never crosses a batch.
    unsigned short* C = p.C[2] + (size_t)(m0 >> 11) * (2048 * 1024);
    const int rloc = (m0 & 2047) + wm;
#pragma unroll
    for (int ni = 0; ni < 4; ++ni) {
      const int col = n0 + wn + ni * 16 + fr;
      const float bb = bias[col];
#pragma unroll
      for (int mi = 0; mi < 8; ++mi) {
        const int rowb = rloc + mi * 16 + q4;
        ushort4 o =
            make_ushort4(f2b(acc[mi][ni][0] + bb), f2b(acc[mi][ni][1] + bb),
                         f2b(acc[mi][ni][2] + bb), f2b(acc[mi][ni][3] + bb));
        *(ushort4*)&C[(size_t)col * 2048 + rowb] = o;
      }
    }
  }
}

// scores[b] = q[b] @ k[b]^T : M=N=2048, K=1024, fp32 out. grid (8,8,4).
__global__ __launch_bounds__(512, 2) void score_gemm8(
    const unsigned short* __restrict__ qb, const unsigned short* __restrict__ kb,
    float* __restrict__ sc) {
  __shared__ __align__(16) unsigned short lds[65536];
  const int bz = blockIdx.z;
  const int m0 = blockIdx.y * 256;
  const int n0 = blockIdx.x * 256;
  f32x4 acc[8][4] = {};
  gemm256_core(qb + (size_t)bz * (2048 * 1024), kb + (size_t)bz * (2048 * 1024),
               1024, 1024, m0, n0, lds, acc);
  store_f32(sc + (size_t)bz * (2048 * 2048), 2048, m0, n0, acc);
}

// part[kh][b] = P[b][:, kh*1024:+1024] @ v[b][kh*1024:+1024, :]. grid (4,8,8).
__global__ __launch_bounds__(512, 2) void pv_gemm8(
    const unsigned short* __restrict__ P, const unsigned short* __restrict__ vT,
    float* __restrict__ parts) {
  __shared__ __align__(16) unsigned short lds[65536];
  const int bz = blockIdx.z >> 1;
  const int kh = blockIdx.z & 1;
  const int m0 = blockIdx.y * 256;
  const int n0 = blockIdx.x * 256;
  f32x4 acc[8][4] = {};
  gemm256_core(P + (size_t)bz * (2048 * 2048) + (size_t)kh * 1024,
               vT + (size_t)bz * (1024 * 2048) + (size_t)kh * 1024, 1024, 2048,
               m0, n0, lds, acc);
  store_f32(parts + (size_t)kh * (4 * 2048 * 1024) +
                (size_t)bz * (2048 * 1024),
            1024, m0, n0, acc);
}

// out = p0 + p1 (split-K reduce), float4.
__global__ __launch_bounds__(256) void add2(const float4* __restrict__ a,
                                            const float4* __restrict__ b,
                                            float4* __restrict__ o, int n4) {
  const int i = blockIdx.x * 256 + threadIdx.x;
  if (i >= n4) return;
  float4 x = a[i], y = b[i];
  o[i] = make_float4(x.x + y.x, x.y + y.y, x.z + y.z, x.w + y.w);
}

// ---------------------------------------------------------------------------
// Merged cast fp32 -> bf16: blockIdx.y selects tensor {q,k,v}.
// ---------------------------------------------------------------------------
__global__ __launch_bounds__(256) void cast3(
    const float4* __restrict__ a, const float4* __restrict__ b,
    const float4* __restrict__ c, ushort4* __restrict__ oa,
    ushort4* __restrict__ ob, ushort4* __restrict__ oc, int n4) {
  const int i = blockIdx.x * 256 + threadIdx.x;
  if (i >= n4) return;
  const float4* src = (blockIdx.y == 0) ? a : (blockIdx.y == 1) ? b : c;
  ushort4* dst = (blockIdx.y == 0) ? oa : (blockIdx.y == 1) ? ob : oc;
  float4 v = src[i];
  dst[i] = make_ushort4(f2b(v.x), f2b(v.y), f2b(v.z), f2b(v.w));
}

// ---------------------------------------------------------------------------
// Merged cast + transpose W [K,N] fp32 -> WT [N,K] bf16; z selects weight.
// ---------------------------------------------------------------------------
__global__ __launch_bounds__(256) void transpose3(
    const float* __restrict__ w0, const float* __restrict__ w1,
    const float* __restrict__ w2, unsigned short* __restrict__ t0,
    unsigned short* __restrict__ t1, unsigned short* __restrict__ t2) {
  __shared__ float t[32][33];
  const int K = 1024, N = 1024;
  const float* W = (blockIdx.z == 0) ? w0 : (blockIdx.z == 1) ? w1 : w2;
  unsigned short* WT = (blockIdx.z == 0) ? t0 : (blockIdx.z == 1) ? t1 : t2;
  const int n0 = blockIdx.x * 32, k0 = blockIdx.y * 32;
  const int tx = threadIdx.x, ty = threadIdx.y;  // block (32,8)
#pragma unroll
  for (int i = 0; i < 32; i += 8)
    t[ty + i][tx] = W[(size_t)(k0 + ty + i) * N + (n0 + tx)];
  __syncthreads();
#pragma unroll
  for (int i = 0; i < 32; i += 8)
    WT[(size_t)(n0 + ty + i) * K + (k0 + tx)] = f2b(t[tx][ty + i]);
}

// ---------------------------------------------------------------------------
// Row softmax: P[row,:] = softmax(BETA * S[row,:]) as bf16. One block/row.
// ---------------------------------------------------------------------------
__global__ __launch_bounds__(256) void softmax_rows(const float* __restrict__ S,
                                                    unsigned short* __restrict__ P) {
  const int cols = 2048;
  const size_t row = blockIdx.x;
  const float4* srow = (const float4*)(S + row * cols);
  const int tid = threadIdx.x;
  const int lane = tid & 63;
  const int wave = tid >> 6;

  float4 a = srow[tid];
  float4 b = srow[tid + 256];

  float mx = fmaxf(fmaxf(fmaxf(a.x, a.y), fmaxf(a.z, a.w)),
                   fmaxf(fmaxf(b.x, b.y), fmaxf(b.z, b.w)));
#pragma unroll
  for (int o = 1; o < 64; o <<= 1) mx = fmaxf(mx, __shfl_xor(mx, o));

  __shared__ float red[8];
  if (lane == 0) red[wave] = mx;
  __syncthreads();
  mx = fmaxf(fmaxf(red[0], red[1]), fmaxf(red[2], red[3]));

  const float c = 0.03125f * 1.4426950408889634f;  // BETA * log2(e)
  float4 pa, pb;
  pa.x = exp2f((a.x - mx) * c); pa.y = exp2f((a.y - mx) * c);
  pa.z = exp2f((a.z - mx) * c); pa.w = exp2f((a.w - mx) * c);
  pb.x = exp2f((b.x - mx) * c); pb.y = exp2f((b.y - mx) * c);
  pb.z = exp2f((b.z - mx) * c); pb.w = exp2f((b.w - mx) * c);

  float sum = pa.x + pa.y + pa.z + pa.w + pb.x + pb.y + pb.z + pb.w;
#pragma unroll
  for (int o = 1; o < 64; o <<= 1) sum += __shfl_xor(sum, o);
  if (lane == 0) red[4 + wave] = sum;
  __syncthreads();
  sum = red[4] + red[5] + red[6] + red[7];

  const float inv = 1.0f / sum;
  ushort4* prow = (ushort4*)(P + row * cols);
  prow[tid] = make_ushort4(f2b(pa.x * inv), f2b(pa.y * inv), f2b(pa.z * inv),
                           f2b(pa.w * inv));
  prow[tid + 256] = make_ushort4(f2b(pb.x * inv), f2b(pb.y * inv),
                                 f2b(pb.z * inv), f2b(pb.w * inv));
}

// ---------------------------------------------------------------------------
extern "C" void kernel_launch(void* const* d_in, const int* in_sizes, int n_in,
                              void* d_out, int out_size, void* d_ws, size_t ws_size,
                              hipStream_t stream) {
  const float* query = (const float*)d_in[0];
  const float* key_ = (const float*)d_in[1];
  const float* value = (const float*)d_in[2];
  const float* Wq = (const float*)d_in[3];
  const float* bq = (const float*)d_in[4];
  const float* Wk = (const float*)d_in[5];
  const float* bk = (const float*)d_in[6];
  const float* Wv = (const float*)d_in[7];
  const float* bv = (const float*)d_in[8];
  float* out = (float*)d_out;

  char* ws = (char*)d_ws;
  // Workspace layout (peak 166 MiB):
  //   [0,6)      WqT/WkT/WvT bf16 [1024,1024]
  //   [6,54)     Xq/Xk/Xv bf16 [8192,1024]   (reused for P after projections)
  //   [54,102)   q bf16 [8192,1024], k bf16 [8192,1024], vT bf16 [4][1024,2048]
  //   [102,166)  scores fp32 [4,2048,2048]   (reused for PV split-K partials)
  unsigned short* WqT = (unsigned short*)ws;
  unsigned short* WkT = WqT + (size_t)1024 * 1024;
  unsigned short* WvT = WkT + (size_t)1024 * 1024;
  unsigned short* Xq = (unsigned short*)(ws + 6 * MIB);
  unsigned short* Xk = Xq + (size_t)8192 * 1024;
  unsigned short* Xv = Xk + (size_t)8192 * 1024;
  unsigned short* qb = (unsigned short*)(ws + 54 * MIB);
  unsigned short* kb = (unsigned short*)(ws + 70 * MIB);
  unsigned short* vT = (unsigned short*)(ws + 86 * MIB);
  float* sc = (float*)(ws + 102 * MIB);
  unsigned short* P = (unsigned short*)(ws + 6 * MIB);  // reuse X region
  float* part0 = sc;                                    // reuse scores region
  float* part1 = sc + (size_t)4 * 2048 * 1024;

  const int n4 = (4 * 2048 * 1024) / 4;
  cast3<<<dim3(n4 / 256, 3), 256, 0, stream>>>(
      (const float4*)query, (const float4*)key_, (const float4*)value,
      (ushort4*)Xq, (ushort4*)Xk, (ushort4*)Xv, n4);

  transpose3<<<dim3(32, 32, 3), dim3(32, 8), 0, stream>>>(Wq, Wk, Wv, WqT, WkT,
                                                          WvT);

  // All three projections: 256x256 tiles, grid (4,32,3) = 384 blocks.
  ProjArgs pa;
  pa.A[0] = Xq;  pa.A[1] = Xk;  pa.A[2] = Xv;
  pa.Bt[0] = WqT; pa.Bt[1] = WkT; pa.Bt[2] = WvT;
  pa.C[0] = qb;  pa.C[1] = kb;  pa.C[2] = vT;
  pa.bias[0] = bq; pa.bias[1] = bk; pa.bias[2] = bv;
  proj_gemm8<<<dim3(4, 32, 3), 512, 0, stream>>>(pa);

  // scores: 256 blocks (1/CU).
  score_gemm8<<<dim3(8, 8, 4), 512, 0, stream>>>(qb, kb, sc);

  // P = softmax(BETA * scores), bf16
  softmax_rows<<<8192, 256, 0, stream>>>(sc, P);

  // PV split-K=2: 256 blocks, partials into dead scores buffer.
  pv_gemm8<<<dim3(4, 8, 8), 512, 0, stream>>>(P, vT, part0);

  // out = part0 + part1 (full 2M float4 coverage: 8192 blocks).
  add2<<<dim3(n4 / 256), 256, 0, stream>>>(
      (const float4*)part0, (const float4*)part1, (float4*)out, n4);
}